// Round 4
// baseline (178.455 us; speedup 1.0000x reference)
//
#include <hip/hip_runtime.h>

#define THREADS 256

typedef __attribute__((ext_vector_type(8))) short bf16x8;
typedef __attribute__((ext_vector_type(4))) float f32x4;

// fp32 -> bf16 round-to-nearest-even
__device__ inline unsigned short f2bf(float f) {
    union { float f; unsigned int u; } v; v.f = f;
    unsigned int r = v.u + 0x7fffu + ((v.u >> 16) & 1u);
    return (unsigned short)(r >> 16);
}
__device__ inline unsigned int pack2(float lo, float hi) {
    return (unsigned int)f2bf(lo) | ((unsigned int)f2bf(hi) << 16);
}
__device__ inline float bflo(unsigned int u) {
    union { unsigned int u; float f; } v; v.u = u << 16; return v.f;
}
__device__ inline float bfhi(unsigned int u) {
    union { unsigned int u; float f; } v; v.u = u & 0xffff0000u; return v.f;
}

// ---------------------------------------------------------------------------
// kP: core fp32 [512,512] -> bf16. 256 blocks.
// ---------------------------------------------------------------------------
__global__ __launch_bounds__(THREADS) void k_convert_core(
    const float* __restrict__ core, unsigned short* __restrict__ coreb)
{
    const int i = blockIdx.x * THREADS + threadIdx.x;   // float4 id
    float4 c = ((const float4*)core)[i];
    ushort4 o;
    o.x = f2bf(c.x); o.y = f2bf(c.y); o.z = f2bf(c.z); o.w = f2bf(c.w);
    ((ushort4*)coreb)[i] = o;
}

// ---------------------------------------------------------------------------
// kA1: u1[n, de, n6] = sum_f x[n, de*16+f] * f5[f, n6].   bf16 out, 16B/thread.
// Pure streaming: no LDS, no barriers. Grid N=4096 blocks.
// ---------------------------------------------------------------------------
__global__ __launch_bounds__(THREADS) void k_a1(
    const float* __restrict__ x, const float* __restrict__ f5,
    uint4* __restrict__ u1b)
{
    const int n = blockIdx.x, t = threadIdx.x;
    const float4* xr = (const float4*)(x + (size_t)n * 4096 + t * 16);
    float4 a0 = xr[0], a1 = xr[1], a2 = xr[2], a3 = xr[3];
    float xv[16] = {a0.x,a0.y,a0.z,a0.w, a1.x,a1.y,a1.z,a1.w,
                    a2.x,a2.y,a2.z,a2.w, a3.x,a3.y,a3.z,a3.w};
    float acc[8] = {0.f,0.f,0.f,0.f,0.f,0.f,0.f,0.f};
    #pragma unroll
    for (int f = 0; f < 16; ++f) {
        #pragma unroll
        for (int q = 0; q < 8; ++q)
            acc[q] = fmaf(xv[f], f5[f*8 + q], acc[q]);   // f5 lane-uniform
    }
    uint4 o;
    o.x = pack2(acc[0], acc[1]); o.y = pack2(acc[2], acc[3]);
    o.z = pack2(acc[4], acc[5]); o.w = pack2(acc[6], acc[7]);
    u1b[(size_t)n * 256 + t] = o;
}

// ---------------------------------------------------------------------------
// kA23: u1b -> u3b.  2 rows/block (grid N/2), R3's verified u2/u3 stages.
//   u2[d,m,n6] = sum_e u1[d*16+e,n6] * f4[e,m]
//   u3[l,m,n6] = sum_d u2[d,m,n6]    * f3[d,l]
// LDS ~29 KB -> 5 blocks/CU.
// ---------------------------------------------------------------------------
__global__ __launch_bounds__(THREADS) void k_a23(
    const uint4* __restrict__ u1b,
    const float* __restrict__ f3, const float* __restrict__ f4,
    unsigned short* __restrict__ u3b)
{
    const int n0 = blockIdx.x * 2;
    const int t  = threadIdx.x;

    __shared__ float fs[256];          // f3 [0..128) | f4 [128..256)
    __shared__ float u1s[2][256 * 9];  // [row][de][n6], pad 9
    __shared__ float u2s[2][128 * 9];  // [row][d*8+m][n6], pad 9

    if (t < 128) { fs[t] = f3[t]; fs[128 + t] = f4[t]; }

    #pragma unroll
    for (int rr = 0; rr < 2; ++rr) {
        uint4 p = u1b[(size_t)(n0 + rr) * 256 + t];
        u1s[rr][t*9 + 0] = bflo(p.x); u1s[rr][t*9 + 1] = bfhi(p.x);
        u1s[rr][t*9 + 2] = bflo(p.y); u1s[rr][t*9 + 3] = bfhi(p.y);
        u1s[rr][t*9 + 4] = bflo(p.z); u1s[rr][t*9 + 5] = bfhi(p.z);
        u1s[rr][t*9 + 6] = bflo(p.w); u1s[rr][t*9 + 7] = bfhi(p.w);
    }
    __syncthreads();

    // u2: thread -> (d = t>>4, m = (t>>1)&7, h = t&1), n6 = 4h..4h+3  [R3 exact]
    {
        const int d = t >> 4, m = (t >> 1) & 7, h = t & 1;
        float fr[16];
        #pragma unroll
        for (int e = 0; e < 16; ++e) fr[e] = fs[128 + e*8 + m];
        float a4[2][4] = {};
        #pragma unroll
        for (int e = 0; e < 16; ++e) {
            const int base = (d*16 + e)*9 + h*4;
            #pragma unroll
            for (int q = 0; q < 4; ++q) {
                a4[0][q] = fmaf(u1s[0][base + q], fr[e], a4[0][q]);
                a4[1][q] = fmaf(u1s[1][base + q], fr[e], a4[1][q]);
            }
        }
        #pragma unroll
        for (int q = 0; q < 4; ++q) {
            u2s[0][(d*8 + m)*9 + h*4 + q] = a4[0][q];
            u2s[1][(d*8 + m)*9 + h*4 + q] = a4[1][q];
        }
    }
    __syncthreads();

    // u3: thread -> (l = t>>5, m = (t>>2)&7, h = t&3); dword idx = t  [R3 exact]
    {
        const int l = t >> 5, m = (t >> 2) & 7, h = t & 3;
        float fr[16];
        #pragma unroll
        for (int d = 0; d < 16; ++d) fr[d] = fs[d*8 + l];
        float a2[2][2] = {};
        #pragma unroll
        for (int d = 0; d < 16; ++d) {
            const int base = (d*8 + m)*9 + h*2;
            a2[0][0] = fmaf(u2s[0][base],     fr[d], a2[0][0]);
            a2[0][1] = fmaf(u2s[0][base + 1], fr[d], a2[0][1]);
            a2[1][0] = fmaf(u2s[1][base],     fr[d], a2[1][0]);
            a2[1][1] = fmaf(u2s[1][base + 1], fr[d], a2[1][1]);
        }
        ((unsigned int*)u3b)[(size_t)(n0+0) * 256 + t] = pack2(a2[0][0], a2[0][1]);
        ((unsigned int*)u3b)[(size_t)(n0+1) * 256 + t] = pack2(a2[1][0], a2[1][1]);
    }
}

// ---------------------------------------------------------------------------
// kB: MFMA GEMM  v[n,p] = sum_q u3[n,q] * core[p,q].  No LDS, no barriers.
// Block tile 64 rows x 32 cols, 4 waves (2x2), wave tile 32x16 (2x1 frags).
// Grid (N/64, 16) = 1024 blocks -> 4 blocks/CU, 16 waves/CU.
// Layouts verified in R2. A/B frag: lane = idx&15, k = (lane>>4)*8 + j.
// C/D: col = lane&15, row = (lane>>4)*4 + reg.
// ---------------------------------------------------------------------------
__global__ __launch_bounds__(THREADS) void k_b(
    const unsigned short* __restrict__ u3b,
    const unsigned short* __restrict__ coreb,
    float* __restrict__ v)
{
    const int t = threadIdx.x, lane = t & 63, w = t >> 6;
    const int m0 = blockIdx.x * 64 + (w >> 1) * 32;
    const int p0 = blockIdx.y * 32 + (w & 1) * 16;
    const int lr = lane & 15, lq = lane >> 4;

    const unsigned short* ap0 = u3b + (size_t)(m0 + lr) * 512 + lq * 8;
    const unsigned short* ap1 = ap0 + 16 * 512;
    const unsigned short* bp  = coreb + (size_t)(p0 + lr) * 512 + lq * 8;

    f32x4 acc0 = {0.f,0.f,0.f,0.f}, acc1 = {0.f,0.f,0.f,0.f};
    #pragma unroll
    for (int k0 = 0; k0 < 512; k0 += 32) {
        bf16x8 a0 = *(const bf16x8*)(ap0 + k0);
        bf16x8 a1 = *(const bf16x8*)(ap1 + k0);
        bf16x8 b  = *(const bf16x8*)(bp  + k0);
        acc0 = __builtin_amdgcn_mfma_f32_16x16x32_bf16(a0, b, acc0, 0, 0, 0);
        acc1 = __builtin_amdgcn_mfma_f32_16x16x32_bf16(a1, b, acc1, 0, 0, 0);
    }
    const int col = p0 + lr, row = m0 + lq * 4;
    #pragma unroll
    for (int q = 0; q < 4; ++q) {
        v[(size_t)(row + q) * 512 + col]      = acc0[q];
        v[(size_t)(row + 16 + q) * 512 + col] = acc1[q];
    }
}

// ---------------------------------------------------------------------------
// kC12: v[n,512] -> w2b[n, ab, k] bf16 (R1's verified w1/w2 stages).
//   w1[a,jk] = sum_i f0[a,i] * v[i*64+jk]
//   w2[ab,k] = sum_j f1[b,j] * w1[a, j*8+k]
// 1 row/block, grid N. LDS ~8 KB.
// ---------------------------------------------------------------------------
__global__ __launch_bounds__(THREADS) void k_c12(
    const float* __restrict__ v,
    const float* __restrict__ f0, const float* __restrict__ f1,
    uint4* __restrict__ w2b)
{
    const int n = blockIdx.x, t = threadIdx.x;
    __shared__ float fs[256];      // f0 | f1
    __shared__ float vs[512];
    __shared__ float w1s[128 * 9]; // [a*8+j][k], pad 9

    if (t < 128) {
        fs[t] = f0[t]; fs[128 + t] = f1[t];
        ((float4*)vs)[t] = ((const float4*)(v + (size_t)n * 512))[t];
    }
    __syncthreads();

    // w1: thread -> (a = t>>4, j = (t>>1)&7, h = t&1), k = 4h..4h+3  [R1 exact]
    {
        const int a = t >> 4, j = (t >> 1) & 7, h = t & 1;
        float fa[8];
        #pragma unroll
        for (int i = 0; i < 8; ++i) fa[i] = fs[a*8 + i];
        float a4[4] = {0.f, 0.f, 0.f, 0.f};
        #pragma unroll
        for (int i = 0; i < 8; ++i) {
            const int base = i*64 + j*8 + h*4;
            #pragma unroll
            for (int q = 0; q < 4; ++q)
                a4[q] = fmaf(vs[base + q], fa[i], a4[q]);
        }
        #pragma unroll
        for (int q = 0; q < 4; ++q) w1s[(a*8 + j)*9 + h*4 + q] = a4[q];
    }
    __syncthreads();

    // w2: thread -> (a = t>>4, b = t&15); write 8 bf16 = 16B coalesced
    {
        const int a = t >> 4, b = t & 15;
        float fb[8];
        #pragma unroll
        for (int j = 0; j < 8; ++j) fb[j] = fs[128 + b*8 + j];
        float a8[8] = {0.f,0.f,0.f,0.f,0.f,0.f,0.f,0.f};
        #pragma unroll
        for (int j = 0; j < 8; ++j) {
            const int base = (a*8 + j)*9;
            #pragma unroll
            for (int k = 0; k < 8; ++k)
                a8[k] = fmaf(w1s[base + k], fb[j], a8[k]);
        }
        uint4 o;
        o.x = pack2(a8[0], a8[1]); o.y = pack2(a8[2], a8[3]);
        o.z = pack2(a8[4], a8[5]); o.w = pack2(a8[6], a8[7]);
        w2b[(size_t)n * 256 + t] = o;   // t == a*16+b == ab
    }
}

// ---------------------------------------------------------------------------
// kC3: y[n, ab*16 + c] = bias + sum_k f2[c,k] * w2[n,ab,k].
// Thread = (ab-group, c-quad); 4 float4 stores, perfectly coalesced.
// One tiny LDS stage for f2 (lane-varying index), 1 barrier. Grid N.
// ---------------------------------------------------------------------------
__global__ __launch_bounds__(THREADS) void k_c3(
    const uint4* __restrict__ w2b, const float* __restrict__ f2,
    const float* __restrict__ bias, float* __restrict__ y)
{
    const int n = blockIdx.x, t = threadIdx.x, cq = t & 3;
    __shared__ float f2s[128];
    if (t < 128) f2s[t] = f2[t];
    __syncthreads();

    float f2r[4][8];
    #pragma unroll
    for (int cc = 0; cc < 4; ++cc)
        #pragma unroll
        for (int k = 0; k < 8; ++k)
            f2r[cc][k] = f2s[(cq*4 + cc)*8 + k];   // 4-addr broadcast, free

    float4* orow = (float4*)(y + (size_t)n * 4096);
    #pragma unroll
    for (int g = 0; g < 4; ++g) {
        const int ab = (t >> 2) + 64 * g;
        uint4 p = w2b[(size_t)n * 256 + ab];
        float wf[8] = {bflo(p.x), bfhi(p.x), bflo(p.y), bfhi(p.y),
                       bflo(p.z), bfhi(p.z), bflo(p.w), bfhi(p.w)};
        float4 o = *(const float4*)(bias + ab*16 + cq*4);
        #pragma unroll
        for (int k = 0; k < 8; ++k) {
            o.x = fmaf(f2r[0][k], wf[k], o.x);
            o.y = fmaf(f2r[1][k], wf[k], o.y);
            o.z = fmaf(f2r[2][k], wf[k], o.z);
            o.w = fmaf(f2r[3][k], wf[k], o.w);
        }
        orow[t + 256 * g] = o;   // float4 idx = ab*4+cq = t + 256g
    }
}

// ---------------------------------------------------------------------------
extern "C" void kernel_launch(void* const* d_in, const int* in_sizes, int n_in,
                              void* d_out, int out_size, void* d_ws, size_t ws_size,
                              hipStream_t stream)
{
    const float* x    = (const float*)d_in[0];
    const float* core = (const float*)d_in[1];
    const float* f0   = (const float*)d_in[2];
    const float* f1   = (const float*)d_in[3];
    const float* f2   = (const float*)d_in[4];
    const float* f3   = (const float*)d_in[5];
    const float* f4   = (const float*)d_in[6];
    const float* f5   = (const float*)d_in[7];
    const float* bias = (const float*)d_in[8];
    float* y = (float*)d_out;

    const int N = in_sizes[0] / 4096;

    // workspace layout (16B-aligned slabs):
    //   u1b  uint4[N*256]      16 MB
    //   w2b  uint4[N*256]      16 MB
    //   v    float[N*512]       8 MB
    //   u3b  ushort[N*512]      4 MB
    //   coreb ushort[512*512]   0.5 MB
    char* p = (char*)d_ws;
    uint4*          u1b   = (uint4*)p;                 p += (size_t)N * 256 * 16;
    uint4*          w2b   = (uint4*)p;                 p += (size_t)N * 256 * 16;
    float*          v     = (float*)p;                 p += (size_t)N * 512 * 4;
    unsigned short* u3b   = (unsigned short*)p;        p += (size_t)N * 512 * 2;
    unsigned short* coreb = (unsigned short*)p;

    k_convert_core<<<256, THREADS, 0, stream>>>(core, coreb);
    k_a1 <<<N, THREADS, 0, stream>>>(x, f5, u1b);
    k_a23<<<N / 2, THREADS, 0, stream>>>(u1b, f3, f4, u3b);
    dim3 gb(N / 64, 16);
    k_b  <<<gb, THREADS, 0, stream>>>(u3b, coreb, v);
    k_c12<<<N, THREADS, 0, stream>>>(v, f0, f1, w2b);
    k_c3 <<<N, THREADS, 0, stream>>>(w2b, f2, bias, y);
}

// Round 5
// 168.956 us; speedup vs baseline: 1.0562x; 1.0562x over previous
//
#include <hip/hip_runtime.h>

#define THREADS 256

typedef __attribute__((ext_vector_type(8))) short bf16x8;
typedef __attribute__((ext_vector_type(4))) float f32x4;

// fp32 -> bf16 round-to-nearest-even
__device__ inline unsigned short f2bf(float f) {
    union { float f; unsigned int u; } v; v.f = f;
    unsigned int r = v.u + 0x7fffu + ((v.u >> 16) & 1u);
    return (unsigned short)(r >> 16);
}
__device__ inline unsigned int pack2(float lo, float hi) {
    return (unsigned int)f2bf(lo) | ((unsigned int)f2bf(hi) << 16);
}

// ---------------------------------------------------------------------------
// Kernel A (R4-exact, verified): in-side contraction, 2 rows/block.
// x[N,4096] -> u3b[N,512] bf16.  Blocks < 256 also convert core -> bf16.
//   u1[d,e,n6] = sum_f x[d,e,f] * f5[f,n6]
//   u2[d,m,n6] = sum_e u1[d,e,n6] * f4[e,m]
//   u3[l,m,n6] = sum_d u2[d,m,n6] * f3[d,l]
// LDS ~29 KB -> 5 blocks/CU -> 20 waves/CU.
// ---------------------------------------------------------------------------
__global__ __launch_bounds__(THREADS) void k_in_contract2(
    const float* __restrict__ x,
    const float* __restrict__ f3, const float* __restrict__ f4,
    const float* __restrict__ f5, const float* __restrict__ core,
    unsigned short* __restrict__ u3b, unsigned short* __restrict__ coreb,
    int N)
{
    const int n0 = blockIdx.x * 2;
    const int t  = threadIdx.x;

    __shared__ float fs[256];          // f3 [0..128) | f4 [128..256)
    __shared__ float u1s[2][256 * 9];  // [row][de][n6], pad 9
    __shared__ float u2s[2][128 * 9];  // [row][d*8+m][n6], pad 9

    if (t < 128) { fs[t] = f3[t]; fs[128 + t] = f4[t]; }

    // side-job: core fp32 -> bf16 (blocks 0..255, 1 float4 per thread)
    if (blockIdx.x < 256) {
        const int i = blockIdx.x * THREADS + t;   // float4 id, 0..65535
        float4 c = ((const float4*)core)[i];
        ushort4 o;
        o.x = f2bf(c.x); o.y = f2bf(c.y); o.z = f2bf(c.z); o.w = f2bf(c.w);
        ((ushort4*)coreb)[i] = o;
    }

    // x chunks for both rows: thread t owns de = t (16 consecutive floats)
    float xv[2][16];
    #pragma unroll
    for (int rr = 0; rr < 2; ++rr) {
        const float4* xr = (const float4*)(x + (size_t)(n0 + rr) * 4096 + t * 16);
        float4 a0 = xr[0], a1 = xr[1], a2 = xr[2], a3 = xr[3];
        xv[rr][0]=a0.x;  xv[rr][1]=a0.y;  xv[rr][2]=a0.z;  xv[rr][3]=a0.w;
        xv[rr][4]=a1.x;  xv[rr][5]=a1.y;  xv[rr][6]=a1.z;  xv[rr][7]=a1.w;
        xv[rr][8]=a2.x;  xv[rr][9]=a2.y;  xv[rr][10]=a2.z; xv[rr][11]=a2.w;
        xv[rr][12]=a3.x; xv[rr][13]=a3.y; xv[rr][14]=a3.z; xv[rr][15]=a3.w;
    }

    // u1: f5 values shared across both rows (lane-uniform -> scalar loads)
    float acc8[2][8];
    #pragma unroll
    for (int q = 0; q < 8; ++q) { acc8[0][q] = 0.f; acc8[1][q] = 0.f; }
    #pragma unroll
    for (int f = 0; f < 16; ++f) {
        #pragma unroll
        for (int n6 = 0; n6 < 8; ++n6) {
            const float w = f5[f*8 + n6];
            acc8[0][n6] = fmaf(xv[0][f], w, acc8[0][n6]);
            acc8[1][n6] = fmaf(xv[1][f], w, acc8[1][n6]);
        }
    }
    __syncthreads();   // fs ready
    #pragma unroll
    for (int n6 = 0; n6 < 8; ++n6) {
        u1s[0][t*9 + n6] = acc8[0][n6];
        u1s[1][t*9 + n6] = acc8[1][n6];
    }
    __syncthreads();

    // u2: thread -> (d = t>>4, m = (t>>1)&7, h = t&1), n6 = 4h..4h+3
    {
        const int d = t >> 4, m = (t >> 1) & 7, h = t & 1;
        float fr[16];
        #pragma unroll
        for (int e = 0; e < 16; ++e) fr[e] = fs[128 + e*8 + m];
        float a4[2][4] = {};
        #pragma unroll
        for (int e = 0; e < 16; ++e) {
            const int base = (d*16 + e)*9 + h*4;
            #pragma unroll
            for (int q = 0; q < 4; ++q) {
                a4[0][q] = fmaf(u1s[0][base + q], fr[e], a4[0][q]);
                a4[1][q] = fmaf(u1s[1][base + q], fr[e], a4[1][q]);
            }
        }
        #pragma unroll
        for (int q = 0; q < 4; ++q) {
            u2s[0][(d*8 + m)*9 + h*4 + q] = a4[0][q];
            u2s[1][(d*8 + m)*9 + h*4 + q] = a4[1][q];
        }
    }
    __syncthreads();

    // u3: thread -> (l = t>>5, m = (t>>2)&7, h = t&3); dword idx = t
    {
        const int l = t >> 5, m = (t >> 2) & 7, h = t & 3;
        float fr[16];
        #pragma unroll
        for (int d = 0; d < 16; ++d) fr[d] = fs[d*8 + l];
        float a2[2][2] = {};
        #pragma unroll
        for (int d = 0; d < 16; ++d) {
            const int base = (d*8 + m)*9 + h*2;
            a2[0][0] = fmaf(u2s[0][base],     fr[d], a2[0][0]);
            a2[0][1] = fmaf(u2s[0][base + 1], fr[d], a2[0][1]);
            a2[1][0] = fmaf(u2s[1][base],     fr[d], a2[1][0]);
            a2[1][1] = fmaf(u2s[1][base + 1], fr[d], a2[1][1]);
        }
        ((unsigned int*)u3b)[(size_t)(n0+0) * 256 + t] = pack2(a2[0][0], a2[0][1]);
        ((unsigned int*)u3b)[(size_t)(n0+1) * 256 + t] = pack2(a2[1][0], a2[1][1]);
    }
}

// ---------------------------------------------------------------------------
// Kernel B (R5-exact, verified): MFMA GEMM  v[n,p] = sum_q u3[n,q]*core[p,q].
// No LDS, no barriers. Block tile 64x32, wave tile 32x16 (2x1 frags).
// Grid (N/64, 16) = 1024 blocks -> 4 blocks/CU, 16 waves/CU.
// A/B frag: lane = idx&15, k = (lane>>4)*8 + j.  C/D: col=lane&15,
// row = (lane>>4)*4 + reg.   [layouts verified R2]
// ---------------------------------------------------------------------------
__global__ __launch_bounds__(THREADS) void k_b(
    const unsigned short* __restrict__ u3b,
    const unsigned short* __restrict__ coreb,
    float* __restrict__ v)
{
    const int t = threadIdx.x, lane = t & 63, w = t >> 6;
    const int m0 = blockIdx.x * 64 + (w >> 1) * 32;
    const int p0 = blockIdx.y * 32 + (w & 1) * 16;
    const int lr = lane & 15, lq = lane >> 4;

    const unsigned short* ap0 = u3b + (size_t)(m0 + lr) * 512 + lq * 8;
    const unsigned short* ap1 = ap0 + 16 * 512;
    const unsigned short* bp  = coreb + (size_t)(p0 + lr) * 512 + lq * 8;

    f32x4 acc0 = {0.f,0.f,0.f,0.f}, acc1 = {0.f,0.f,0.f,0.f};
    #pragma unroll
    for (int k0 = 0; k0 < 512; k0 += 32) {
        bf16x8 a0 = *(const bf16x8*)(ap0 + k0);
        bf16x8 a1 = *(const bf16x8*)(ap1 + k0);
        bf16x8 b  = *(const bf16x8*)(bp  + k0);
        acc0 = __builtin_amdgcn_mfma_f32_16x16x32_bf16(a0, b, acc0, 0, 0, 0);
        acc1 = __builtin_amdgcn_mfma_f32_16x16x32_bf16(a1, b, acc1, 0, 0, 0);
    }
    const int col = p0 + lr, row = m0 + lq * 4;
    #pragma unroll
    for (int q = 0; q < 4; ++q) {
        v[(size_t)(row + q) * 512 + col]      = acc0[q];
        v[(size_t)(row + 16 + q) * 512 + col] = acc1[q];
    }
}

// ---------------------------------------------------------------------------
// Kernel C (R1-exact, verified): out-side expansion v[N,512] -> y[N,4096]+bias.
// One block per batch row, ~17 KB LDS -> 9 blocks/CU (occupancy-capped 32 w/CU).
// ---------------------------------------------------------------------------
__global__ __launch_bounds__(THREADS) void k_out_expand(
    const float* __restrict__ v,
    const float* __restrict__ f0, const float* __restrict__ f1,
    const float* __restrict__ f2, const float* __restrict__ bias,
    float* __restrict__ y, int N)
{
    const int n = blockIdx.x;
    const int t = threadIdx.x;

    __shared__ float fs[256];        // f0 [0..128) | f1 [128..256)
    __shared__ float vs[512];
    __shared__ float w1s[128 * 9];   // [a*8+j][k], pad 9
    __shared__ float w2s[256 * 9];   // [a*16+b][k], pad 9

    if (t < 128) { fs[t] = f0[t]; fs[128 + t] = f1[t]; }
    if (t < 128) ((float4*)vs)[t] = ((const float4*)(v + (size_t)n*512))[t];
    __syncthreads();

    // w1: thread -> (a = t>>4, j = (t>>1)&7, h = t&1), k = 4h..4h+3
    {
        const int a = t >> 4, j = (t >> 1) & 7, h = t & 1;
        float fr[8];
        #pragma unroll
        for (int i = 0; i < 8; ++i) fr[i] = fs[a*8 + i];
        float a4[4] = {0.f, 0.f, 0.f, 0.f};
        #pragma unroll
        for (int i = 0; i < 8; ++i) {
            const int base = i*64 + j*8 + h*4;
            #pragma unroll
            for (int q = 0; q < 4; ++q)
                a4[q] = fmaf(vs[base + q], fr[i], a4[q]);
        }
        #pragma unroll
        for (int q = 0; q < 4; ++q) w1s[(a*8 + j)*9 + h*4 + q] = a4[q];
    }
    __syncthreads();

    // w2: thread -> (a = t>>4, b = t&15), all k
    {
        const int a = t >> 4, b = t & 15;
        float fr[8];
        #pragma unroll
        for (int j = 0; j < 8; ++j) fr[j] = fs[128 + b*8 + j];
        float a8[8] = {0.f,0.f,0.f,0.f,0.f,0.f,0.f,0.f};
        #pragma unroll
        for (int j = 0; j < 8; ++j) {
            const int base = (a*8 + j)*9;
            const float fj = fr[j];
            #pragma unroll
            for (int k = 0; k < 8; ++k)
                a8[k] = fmaf(w1s[base + k], fj, a8[k]);
        }
        #pragma unroll
        for (int k = 0; k < 8; ++k) w2s[(a*16 + b)*9 + k] = a8[k];
    }
    __syncthreads();

    // y: thread -> (a = t>>4, b = t&15), c = 0..15
    {
        const int a = t >> 4, b = t & 15;
        float wr[8];
        #pragma unroll
        for (int k = 0; k < 8; ++k) wr[k] = w2s[(a*16 + b)*9 + k];

        const int obase = a*256 + b*16;   // == t*16
        float4 b4[4];
        {
            const float4* bp = (const float4*)(bias + obase);
            b4[0] = bp[0]; b4[1] = bp[1]; b4[2] = bp[2]; b4[3] = bp[3];
        }
        float yv[16];
        #pragma unroll
        for (int q = 0; q < 4; ++q) {
            yv[q*4+0] = b4[q].x; yv[q*4+1] = b4[q].y;
            yv[q*4+2] = b4[q].z; yv[q*4+3] = b4[q].w;
        }
        #pragma unroll
        for (int c = 0; c < 16; ++c) {
            float s = yv[c];
            #pragma unroll
            for (int k = 0; k < 8; ++k)
                s = fmaf(wr[k], f2[c*8 + k], s);   // f2 lane-uniform -> s_load
            yv[c] = s;
        }
        float4* o = (float4*)(y + (size_t)n*4096 + obase);
        #pragma unroll
        for (int q = 0; q < 4; ++q)
            o[q] = make_float4(yv[q*4+0], yv[q*4+1], yv[q*4+2], yv[q*4+3]);
    }
}

// ---------------------------------------------------------------------------
extern "C" void kernel_launch(void* const* d_in, const int* in_sizes, int n_in,
                              void* d_out, int out_size, void* d_ws, size_t ws_size,
                              hipStream_t stream)
{
    const float* x    = (const float*)d_in[0];
    const float* core = (const float*)d_in[1];
    const float* f0   = (const float*)d_in[2];
    const float* f1   = (const float*)d_in[3];
    const float* f2   = (const float*)d_in[4];
    const float* f3   = (const float*)d_in[5];
    const float* f4   = (const float*)d_in[6];
    const float* f5   = (const float*)d_in[7];
    const float* bias = (const float*)d_in[8];
    float* y = (float*)d_out;

    const int N = in_sizes[0] / 4096;

    // workspace: u3b bf16 [N,512] (4MB) | coreb bf16 [512,512] (0.5MB) | v fp32 [N,512] (8MB)
    unsigned short* u3b   = (unsigned short*)d_ws;
    unsigned short* coreb = u3b + (size_t)N * 512;
    float*          v     = (float*)(coreb + 512 * 512);

    k_in_contract2<<<N / 2, THREADS, 0, stream>>>(x, f3, f4, f5, core, u3b, coreb, N);
    dim3 gb(N / 64, 16);
    k_b<<<gb, THREADS, 0, stream>>>(u3b, coreb, v);
    k_out_expand<<<N, THREADS, 0, stream>>>(v, f0, f1, f2, bias, y, N);
}